// Round 11
// baseline (15.955 us; speedup 1.0000x reference)
//
#include <hip/hip_runtime.h>

#define B_    8
#define N_    128
#define NB_   32
#define NORB_ 128
#define RPB   32     // rows per block
#define OPB   16     // orbitals per block
#define THREADS 512
#define RPAD  20     // red row stride (16 used + 4 pad, float4-aligned)

__global__ __launch_bounds__(THREADS, 2) void bobf_kernel(
    const float* __restrict__ chi,
    const float* __restrict__ W,
    float* __restrict__ out)
{
    __shared__ float Sp[16][NB_];                      // 2 KB
    __shared__ float S[NB_];
    __shared__ __align__(16) float xT[NB_][RPB];       // xT[l][r], 4 KB
    __shared__ __align__(16) float red[32][RPB][RPAD]; // 80 KB

    const int t   = threadIdx.x;
    const int blk = blockIdx.x;
    const int b    = blk >> 5;            // 0..7
    const int rowg = (blk >> 3) & 3;      // 0..3
    const int og   = blk & 7;             // 0..7
    const int i0   = rowg * RPB;
    const int o0   = og * OPB;

    // ---- Stage 1: S[k] partials (coalesced) + xT build (32 rows) ----
    {
        const int k = t & 31;
        const int g = t >> 5;                          // 0..15, 8 rows each
        const float* base = chi + (b * N_) * NB_ + k;
        float s = 0.f;
        #pragma unroll
        for (int jj = 0; jj < 8; ++jj) s += base[(g * 8 + jj) * NB_];
        Sp[g][k] = s;
    }
    #pragma unroll
    for (int e = 0; e < 2; ++e) {                      // 1024 xT entries, 512 thr
        const int idx = t + e * THREADS;
        const int r = idx >> 5, l = idx & 31;
        xT[l][r] = chi[(b * N_ + i0 + r) * NB_ + l];
    }
    __syncthreads();
    if (t < NB_) {
        float s = 0.f;
        #pragma unroll
        for (int g = 0; g < 16; ++g) s += Sp[g][t];
        S[t] = s;
    }
    __syncthreads();

    // ---- Main: thread = (q, rg, oq); 8 rows x 4 orbitals ----
    const int q  = t >> 4;               // 0..31  (k == q within chunk)
    const int rg = (t >> 2) & 3;         // 0..3
    const int oq = t & 3;                // 0..3
    const int r0 = rg * 8;

    const float inv = 1.0f / (float)(N_ - 1);
    const float Sq = S[q];
    float y[8];
    {
        const float4 xa = *(const float4*)&xT[q][r0];
        const float4 xb = *(const float4*)&xT[q][r0 + 4];
        y[0] = (Sq - xa.x) * inv; y[1] = (Sq - xa.y) * inv;
        y[2] = (Sq - xa.z) * inv; y[3] = (Sq - xa.w) * inv;
        y[4] = (Sq - xb.x) * inv; y[5] = (Sq - xb.y) * inv;
        y[6] = (Sq - xb.z) * inv; y[7] = (Sq - xb.w) * inv;
    }

    const float4* Wf  = (const float4*)(W + (q * 32) * NORB_ + o0 + oq * 4);
    const float*  xjp = &xT[0][r0];

    float4 a0 = {0,0,0,0}, a1 = {0,0,0,0}, a2 = {0,0,0,0}, a3 = {0,0,0,0};
    float4 a4 = {0,0,0,0}, a5 = {0,0,0,0}, a6 = {0,0,0,0}, a7 = {0,0,0,0};

    // ---- Register double-buffered W pipeline: 4 groups of 8 j's ----
    float4 wA[8], wB[8];
    #pragma unroll
    for (int u = 0; u < 8; ++u) wA[u] = Wf[u * (NORB_ / 4)];   // prefetch group 0

    #pragma unroll
    for (int g = 0; g < 4; ++g) {
        // prefetch next group into the other buffer (g compile-time via unroll)
        if (g < 3) {
            if ((g & 1) == 0) {
                #pragma unroll
                for (int u = 0; u < 8; ++u) wB[u] = Wf[((g + 1) * 8 + u) * (NORB_ / 4)];
            } else {
                #pragma unroll
                for (int u = 0; u < 8; ++u) wA[u] = Wf[((g + 1) * 8 + u) * (NORB_ / 4)];
            }
        }
        // compute current group from the buffer loaded last
        #pragma unroll
        for (int u = 0; u < 8; ++u) {
            const int j = g * 8 + u;
            const float4 wv = ((g & 1) == 0) ? wA[u] : wB[u];
            const float4 xva = *(const float4*)(xjp + j * RPB);      // xT[j][r0..r0+3]
            const float4 xvb = *(const float4*)(xjp + j * RPB + 4);  // xT[j][r0+4..r0+7]
            const float p0 = y[0] * xva.x;
            const float p1 = y[1] * xva.y;
            const float p2 = y[2] * xva.z;
            const float p3 = y[3] * xva.w;
            const float p4 = y[4] * xvb.x;
            const float p5 = y[5] * xvb.y;
            const float p6 = y[6] * xvb.z;
            const float p7 = y[7] * xvb.w;
            a0.x += p0 * wv.x; a0.y += p0 * wv.y; a0.z += p0 * wv.z; a0.w += p0 * wv.w;
            a1.x += p1 * wv.x; a1.y += p1 * wv.y; a1.z += p1 * wv.z; a1.w += p1 * wv.w;
            a2.x += p2 * wv.x; a2.y += p2 * wv.y; a2.z += p2 * wv.z; a2.w += p2 * wv.w;
            a3.x += p3 * wv.x; a3.y += p3 * wv.y; a3.z += p3 * wv.z; a3.w += p3 * wv.w;
            a4.x += p4 * wv.x; a4.y += p4 * wv.y; a4.z += p4 * wv.z; a4.w += p4 * wv.w;
            a5.x += p5 * wv.x; a5.y += p5 * wv.y; a5.z += p5 * wv.z; a5.w += p5 * wv.w;
            a6.x += p6 * wv.x; a6.y += p6 * wv.y; a6.z += p6 * wv.z; a6.w += p6 * wv.w;
            a7.x += p7 * wv.x; a7.y += p7 * wv.y; a7.z += p7 * wv.z; a7.w += p7 * wv.w;
        }
    }

    // ---- Epilogue: partials -> LDS -> 32-way q-reduce ----
    {
        float* rq = &red[q][0][0] + oq * 4;
        *(float4*)&rq[(r0 + 0) * RPAD] = a0;
        *(float4*)&rq[(r0 + 1) * RPAD] = a1;
        *(float4*)&rq[(r0 + 2) * RPAD] = a2;
        *(float4*)&rq[(r0 + 3) * RPAD] = a3;
        *(float4*)&rq[(r0 + 4) * RPAD] = a4;
        *(float4*)&rq[(r0 + 5) * RPAD] = a5;
        *(float4*)&rq[(r0 + 6) * RPAD] = a6;
        *(float4*)&rq[(r0 + 7) * RPAD] = a7;
    }
    __syncthreads();
    {
        const int r = t >> 4, o = t & 15;              // 512 outputs
        float v = 0.f;
        #pragma unroll
        for (int qq = 0; qq < 32; ++qq) v += red[qq][r][o];
        out[(b * N_ + i0 + r) * NORB_ + o0 + o] = v;
    }
}

extern "C" void kernel_launch(void* const* d_in, const int* in_sizes, int n_in,
                              void* d_out, int out_size, void* d_ws, size_t ws_size,
                              hipStream_t stream) {
    const float* chi = (const float*)d_in[0];
    const float* W   = (const float*)d_in[1];
    float* out = (float*)d_out;
    dim3 grid(B_ * (N_ / RPB) * (NORB_ / OPB));   // 8*4*8 = 256 blocks
    dim3 block(THREADS);
    hipLaunchKernelGGL(bobf_kernel, grid, block, 0, stream, chi, W, out);
}

// Round 12
// 12.329 us; speedup vs baseline: 1.2941x; 1.2941x over previous
//
#include <hip/hip_runtime.h>

#define B_    8
#define N_    128
#define NB_   32
#define NORB_ 128
#define RPB   32     // rows per block
#define OPB   16     // orbitals per block
#define THREADS 512
#define RPAD  20     // red row stride (16 used + 4 pad, float4-aligned)

__global__ __launch_bounds__(THREADS, 2) void bobf_kernel(
    const float* __restrict__ chi,
    const float* __restrict__ W,
    float* __restrict__ out)
{
    __shared__ __align__(16) float wlds[1024 * 16];      // 64 KB: W[:, o0:o0+16]
    __shared__ float Sp[16][NB_];                        // 2 KB
    __shared__ float S[NB_];
    __shared__ __align__(16) float xT[NB_][RPB];         // 4 KB
    __shared__ __align__(16) float red[32][RPB][RPAD];   // 80 KB

    const int t   = threadIdx.x;
    const int blk = blockIdx.x;
    const int b    = blk >> 5;            // 0..7
    const int rowg = (blk >> 3) & 3;      // 0..3
    const int og   = blk & 7;             // 0..7
    const int i0   = rowg * RPB;
    const int o0   = og * OPB;

    // ---- 1) W slice -> regs: issued FIRST so cold HBM fetch starts at t=0 ----
    float4 wreg[8];
    #pragma unroll
    for (int e = 0; e < 8; ++e) {
        const int lin = e * THREADS + t;                 // 16B-chunk index, 0..4095
        const int kl  = lin >> 2;
        const int oqs = lin & 3;
        wreg[e] = *(const float4*)(W + kl * NORB_ + o0 + oqs * 4);
    }

    // ---- 2) chi stage-1: S partials (coalesced) + xT build (32 rows) ----
    {
        const int k = t & 31;
        const int g = t >> 5;                            // 0..15, 8 rows each
        const float* base = chi + (b * N_) * NB_ + k;
        float s = 0.f;
        #pragma unroll
        for (int jj = 0; jj < 8; ++jj) s += base[(g * 8 + jj) * NB_];
        Sp[g][k] = s;
    }
    #pragma unroll
    for (int e = 0; e < 2; ++e) {                        // 1024 xT entries
        const int idx = t + e * THREADS;
        const int r = idx >> 5, l = idx & 31;
        xT[l][r] = chi[(b * N_ + i0 + r) * NB_ + l];
    }

    // ---- 3) W regs -> LDS (conflict-free: 64 distinct chunks span all banks) ----
    #pragma unroll
    for (int e = 0; e < 8; ++e) {
        const int lin = e * THREADS + t;
        const int kl  = lin >> 2;
        const int oqs = lin & 3;
        *(float4*)&wlds[kl * 16 + oqs * 4] = wreg[e];
    }
    __syncthreads();
    if (t < NB_) {
        float s = 0.f;
        #pragma unroll
        for (int g = 0; g < 16; ++g) s += Sp[g][t];
        S[t] = s;
    }
    __syncthreads();

    // ---- Main: thread = (q, rg, oq); 8 rows x 4 orbitals, all operands in LDS ----
    const int q  = t >> 4;               // 0..31  (k == q within chunk)
    const int rg = (t >> 2) & 3;         // 0..3
    const int oq = t & 3;                // 0..3
    const int r0 = rg * 8;

    const float inv = 1.0f / (float)(N_ - 1);
    const float Sq = S[q];
    float y[8];
    {
        const float4 xa = *(const float4*)&xT[q][r0];
        const float4 xb = *(const float4*)&xT[q][r0 + 4];
        y[0] = (Sq - xa.x) * inv; y[1] = (Sq - xa.y) * inv;
        y[2] = (Sq - xa.z) * inv; y[3] = (Sq - xa.w) * inv;
        y[4] = (Sq - xb.x) * inv; y[5] = (Sq - xb.y) * inv;
        y[6] = (Sq - xb.z) * inv; y[7] = (Sq - xb.w) * inv;
    }

    const float* xjp = &xT[0][r0];
    const float* wp  = &wlds[q * 512 + oq * 4];          // W row q*32, cols oq*4..+3

    float4 a0 = {0,0,0,0}, a1 = {0,0,0,0}, a2 = {0,0,0,0}, a3 = {0,0,0,0};
    float4 a4 = {0,0,0,0}, a5 = {0,0,0,0}, a6 = {0,0,0,0}, a7 = {0,0,0,0};
    #pragma unroll 8
    for (int j = 0; j < 32; ++j) {
        const float4 xva = *(const float4*)(xjp + j * RPB);      // xT[j][r0..r0+3]
        const float4 xvb = *(const float4*)(xjp + j * RPB + 4);  // xT[j][r0+4..r0+7]
        const float4 wv  = *(const float4*)(wp + j * 16);        // wlds[q*32+j][oq*4..]
        const float p0 = y[0] * xva.x;
        const float p1 = y[1] * xva.y;
        const float p2 = y[2] * xva.z;
        const float p3 = y[3] * xva.w;
        const float p4 = y[4] * xvb.x;
        const float p5 = y[5] * xvb.y;
        const float p6 = y[6] * xvb.z;
        const float p7 = y[7] * xvb.w;
        a0.x += p0 * wv.x; a0.y += p0 * wv.y; a0.z += p0 * wv.z; a0.w += p0 * wv.w;
        a1.x += p1 * wv.x; a1.y += p1 * wv.y; a1.z += p1 * wv.z; a1.w += p1 * wv.w;
        a2.x += p2 * wv.x; a2.y += p2 * wv.y; a2.z += p2 * wv.z; a2.w += p2 * wv.w;
        a3.x += p3 * wv.x; a3.y += p3 * wv.y; a3.z += p3 * wv.z; a3.w += p3 * wv.w;
        a4.x += p4 * wv.x; a4.y += p4 * wv.y; a4.z += p4 * wv.z; a4.w += p4 * wv.w;
        a5.x += p5 * wv.x; a5.y += p5 * wv.y; a5.z += p5 * wv.z; a5.w += p5 * wv.w;
        a6.x += p6 * wv.x; a6.y += p6 * wv.y; a6.z += p6 * wv.z; a6.w += p6 * wv.w;
        a7.x += p7 * wv.x; a7.y += p7 * wv.y; a7.z += p7 * wv.z; a7.w += p7 * wv.w;
    }

    // ---- Epilogue: partials -> LDS -> 32-way q-reduce (identical to R10) ----
    {
        float* rq = &red[q][0][0] + oq * 4;
        *(float4*)&rq[(r0 + 0) * RPAD] = a0;
        *(float4*)&rq[(r0 + 1) * RPAD] = a1;
        *(float4*)&rq[(r0 + 2) * RPAD] = a2;
        *(float4*)&rq[(r0 + 3) * RPAD] = a3;
        *(float4*)&rq[(r0 + 4) * RPAD] = a4;
        *(float4*)&rq[(r0 + 5) * RPAD] = a5;
        *(float4*)&rq[(r0 + 6) * RPAD] = a6;
        *(float4*)&rq[(r0 + 7) * RPAD] = a7;
    }
    __syncthreads();
    {
        const int r = t >> 4, o = t & 15;              // 512 outputs
        float v = 0.f;
        #pragma unroll
        for (int qq = 0; qq < 32; ++qq) v += red[qq][r][o];
        out[(b * N_ + i0 + r) * NORB_ + o0 + o] = v;
    }
}

extern "C" void kernel_launch(void* const* d_in, const int* in_sizes, int n_in,
                              void* d_out, int out_size, void* d_ws, size_t ws_size,
                              hipStream_t stream) {
    const float* chi = (const float*)d_in[0];
    const float* W   = (const float*)d_in[1];
    float* out = (float*)d_out;
    dim3 grid(B_ * (N_ / RPB) * (NORB_ / OPB));   // 8*4*8 = 256 blocks
    dim3 block(THREADS);
    hipLaunchKernelGGL(bobf_kernel, grid, block, 0, stream, chi, W, out);
}

// Round 13
// 11.658 us; speedup vs baseline: 1.3686x; 1.0576x over previous
//
#include <hip/hip_runtime.h>

#define B_    8
#define N_    128
#define NB_   32
#define NORB_ 128
#define RPB   32     // rows per block
#define OPB   16     // orbitals per block
#define THREADS 512
#define RPAD  20     // red row stride (16 used + 4 pad, float4-aligned)

__global__ __launch_bounds__(THREADS, 2) void bobf_kernel(
    const float* __restrict__ chi,
    const float* __restrict__ W,
    float* __restrict__ out)
{
    __shared__ float Sp[16][NB_];                      // 2 KB
    __shared__ float S[NB_];
    __shared__ __align__(16) float xT[NB_][RPB];       // xT[l][r], 4 KB
    __shared__ __align__(16) float red[32][RPB][RPAD]; // 80 KB

    const int t   = threadIdx.x;
    const int blk = blockIdx.x;
    const int b    = blk >> 5;            // 0..7
    const int rowg = (blk >> 3) & 3;      // 0..3
    const int og_b = blk & 7;             // 0..7
    const int i0   = rowg * RPB;
    const int o0   = og_b * OPB;

    // ---- Stage 1: S[k] partials (coalesced) + xT build (32 rows) ----
    {
        const int k = t & 31;
        const int g = t >> 5;                          // 0..15, 8 rows each
        const float* base = chi + (b * N_) * NB_ + k;
        float s = 0.f;
        #pragma unroll
        for (int jj = 0; jj < 8; ++jj) s += base[(g * 8 + jj) * NB_];
        Sp[g][k] = s;
    }
    #pragma unroll
    for (int e = 0; e < 2; ++e) {                      // 1024 xT entries, 512 thr
        const int idx = t + e * THREADS;
        const int r = idx >> 5, l = idx & 31;
        xT[l][r] = chi[(b * N_ + i0 + r) * NB_ + l];
    }
    __syncthreads();
    if (t < NB_) {
        float s = 0.f;
        #pragma unroll
        for (int g = 0; g < 16; ++g) s += Sp[g][t];
        S[t] = s;
    }
    __syncthreads();

    // ---- Main: thread = (q, rg, og); 4 rows x 8 orbitals, y factored out ----
    const int q  = t >> 4;               // 0..31  (k == q within chunk)
    const int rg = (t >> 1) & 7;         // 0..7
    const int og = t & 1;                // 0..1
    const int r0 = rg * 4;

    const float* xjp = &xT[0][r0];
    const float* Wp  = W + (q * 32) * NORB_ + o0 + og * 8;

    // inner[r][o] accumulators: 4 rows x 8 orbitals (no y yet)
    float4 a00 = {0,0,0,0}, a01 = {0,0,0,0};
    float4 a10 = {0,0,0,0}, a11 = {0,0,0,0};
    float4 a20 = {0,0,0,0}, a21 = {0,0,0,0};
    float4 a30 = {0,0,0,0}, a31 = {0,0,0,0};
    #pragma unroll 8
    for (int j = 0; j < 32; ++j) {
        const float4 xv = *(const float4*)(xjp + j * RPB);   // xT[j][r0..r0+3]
        const float4 w0 = *(const float4*)(Wp + j * NORB_);      // o..o+3
        const float4 w1 = *(const float4*)(Wp + j * NORB_ + 4);  // o+4..o+7
        a00.x += xv.x * w0.x; a00.y += xv.x * w0.y; a00.z += xv.x * w0.z; a00.w += xv.x * w0.w;
        a01.x += xv.x * w1.x; a01.y += xv.x * w1.y; a01.z += xv.x * w1.z; a01.w += xv.x * w1.w;
        a10.x += xv.y * w0.x; a10.y += xv.y * w0.y; a10.z += xv.y * w0.z; a10.w += xv.y * w0.w;
        a11.x += xv.y * w1.x; a11.y += xv.y * w1.y; a11.z += xv.y * w1.z; a11.w += xv.y * w1.w;
        a20.x += xv.z * w0.x; a20.y += xv.z * w0.y; a20.z += xv.z * w0.z; a20.w += xv.z * w0.w;
        a21.x += xv.z * w1.x; a21.y += xv.z * w1.y; a21.z += xv.z * w1.z; a21.w += xv.z * w1.w;
        a30.x += xv.w * w0.x; a30.y += xv.w * w0.y; a30.z += xv.w * w0.z; a30.w += xv.w * w0.w;
        a31.x += xv.w * w1.x; a31.y += xv.w * w1.y; a31.z += xv.w * w1.z; a31.w += xv.w * w1.w;
    }

    // ---- Apply y[r] once, write partials ----
    const float inv = 1.0f / (float)(N_ - 1);
    const float Sq = S[q];
    const float4 xq = *(const float4*)&xT[q][r0];
    const float y0 = (Sq - xq.x) * inv;
    const float y1 = (Sq - xq.y) * inv;
    const float y2 = (Sq - xq.z) * inv;
    const float y3 = (Sq - xq.w) * inv;
    a00.x *= y0; a00.y *= y0; a00.z *= y0; a00.w *= y0;
    a01.x *= y0; a01.y *= y0; a01.z *= y0; a01.w *= y0;
    a10.x *= y1; a10.y *= y1; a10.z *= y1; a10.w *= y1;
    a11.x *= y1; a11.y *= y1; a11.z *= y1; a11.w *= y1;
    a20.x *= y2; a20.y *= y2; a20.z *= y2; a20.w *= y2;
    a21.x *= y2; a21.y *= y2; a21.z *= y2; a21.w *= y2;
    a30.x *= y3; a30.y *= y3; a30.z *= y3; a30.w *= y3;
    a31.x *= y3; a31.y *= y3; a31.z *= y3; a31.w *= y3;

    {
        float* rq = &red[q][0][0] + og * 8;
        *(float4*)&rq[(r0 + 0) * RPAD]     = a00;
        *(float4*)&rq[(r0 + 0) * RPAD + 4] = a01;
        *(float4*)&rq[(r0 + 1) * RPAD]     = a10;
        *(float4*)&rq[(r0 + 1) * RPAD + 4] = a11;
        *(float4*)&rq[(r0 + 2) * RPAD]     = a20;
        *(float4*)&rq[(r0 + 2) * RPAD + 4] = a21;
        *(float4*)&rq[(r0 + 3) * RPAD]     = a30;
        *(float4*)&rq[(r0 + 3) * RPAD + 4] = a31;
    }
    __syncthreads();
    {
        const int r = t >> 4, o = t & 15;              // 512 outputs
        float v = 0.f;
        #pragma unroll
        for (int qq = 0; qq < 32; ++qq) v += red[qq][r][o];
        out[(b * N_ + i0 + r) * NORB_ + o0 + o] = v;
    }
}

extern "C" void kernel_launch(void* const* d_in, const int* in_sizes, int n_in,
                              void* d_out, int out_size, void* d_ws, size_t ws_size,
                              hipStream_t stream) {
    const float* chi = (const float*)d_in[0];
    const float* W   = (const float*)d_in[1];
    float* out = (float*)d_out;
    dim3 grid(B_ * (N_ / RPB) * (NORB_ / OPB));   // 8*4*8 = 256 blocks
    dim3 block(THREADS);
    hipLaunchKernelGGL(bobf_kernel, grid, block, 0, stream, chi, W, out);
}

// Round 14
// 9.854 us; speedup vs baseline: 1.6191x; 1.1830x over previous
//
#include <hip/hip_runtime.h>
#include <hip/hip_bf16.h>

#define B_    8
#define N_    128
#define NB_   32
#define NORB_ 128
#define RPB   32     // rows per block
#define OPB   16     // orbitals per block
#define THREADS 256

using bf16x8 = __attribute__((ext_vector_type(8))) short;
using f32x4  = __attribute__((ext_vector_type(4))) float;

__global__ __launch_bounds__(THREADS) void bobf_kernel(
    const float* __restrict__ chi,
    const float* __restrict__ W,
    float* __restrict__ out)
{
    __shared__ float wt[1024][18];                  // 72 KB: W[:, o0:o0+16], pad 18
    __shared__ float Sp[8][NB_];                    // 1 KB
    __shared__ float S[NB_];
    __shared__ __align__(16) float xr_[RPB][36];    // x rows, 4.6 KB
    __shared__ float yr_[RPB][36];                  // y rows, 4.6 KB
    __shared__ float red2[4][RPB][20];              // 10.2 KB

    const int t   = threadIdx.x;
    const int blk = blockIdx.x;
    const int b    = blk >> 5;            // 0..7
    const int rowg = (blk >> 3) & 3;      // 0..3
    const int og   = blk & 7;             // 0..7  (== XCD id -> perfect W reuse in L2)
    const int i0   = rowg * RPB;
    const int o0   = og * OPB;

    // ---- 1) Stage W slice -> LDS f32 (issued first; overlaps prologue) ----
    // 1024 rows x 16 cols as float2 chunks: c = e*256+t: kl=c>>3, cc=c&7
    #pragma unroll
    for (int e = 0; e < 32; ++e) {
        const int c  = e * THREADS + t;
        const int kl = c >> 3, cc = c & 7;
        const float2 v = *(const float2*)(W + kl * NORB_ + o0 + cc * 2);
        *(float2*)&wt[kl][cc * 2] = v;               // 18*kl+2cc even -> 8B aligned
    }

    // ---- 2) S partials + x rows ----
    {
        const int k = t & 31;
        const int g = t >> 5;                        // 0..7, 16 rows each
        const float* base = chi + (b * N_) * NB_ + k;
        float s = 0.f;
        #pragma unroll
        for (int jj = 0; jj < 16; ++jj) s += base[(g * 16 + jj) * NB_];
        Sp[g][k] = s;
    }
    #pragma unroll
    for (int e = 0; e < 4; ++e) {                    // 1024 x-entries
        const int idx = e * THREADS + t;
        const int r = idx >> 5, l = idx & 31;
        xr_[r][l] = chi[(b * N_ + i0 + r) * NB_ + l];
    }
    __syncthreads();
    if (t < NB_) {
        float s = 0.f;
        #pragma unroll
        for (int g = 0; g < 8; ++g) s += Sp[g][t];
        S[t] = s;
    }
    __syncthreads();
    {
        const float inv = 1.0f / (float)(N_ - 1);
        #pragma unroll
        for (int e = 0; e < 4; ++e) {                // y[r][q] = (S[q]-x[r][q])/127
            const int idx = e * THREADS + t;
            const int r = idx >> 5, q = idx & 31;
            yr_[r][q] = (S[q] - xr_[r][q]) * inv;
        }
    }
    __syncthreads();

    // ---- Main: wave wv owns ksteps wv*8..wv*8+7; two 16-row M-tiles ----
    const int wv   = t >> 6;             // 0..3
    const int lane = t & 63;
    const int lr = lane & 15;            // A row-in-tile / B col / C col
    const int lg = lane >> 4;            // k-group 0..3
    const int l0 = lg * 8;

    float xa0[8], xa1[8];                // x[r][l0..l0+7], loaded once
    #pragma unroll
    for (int e = 0; e < 8; ++e) {
        xa0[e] = xr_[lr][l0 + e];
        xa1[e] = xr_[16 + lr][l0 + e];
    }

    f32x4 acc0 = {0.f, 0.f, 0.f, 0.f};
    f32x4 acc1 = {0.f, 0.f, 0.f, 0.f};

    #pragma unroll
    for (int ks = 0; ks < 8; ++ks) {
        const int kstep = wv * 8 + ks;
        // B frag: W[kstep*32 + l0 + e][o0 + lr]  (2-way bank max)
        bf16x8 bf;
        #pragma unroll
        for (int e = 0; e < 8; ++e) {
            const float w0 = wt[kstep * 32 + l0 + e][lr];
            bf[e] = (short)__bfloat16_as_ushort(__float2bfloat16(w0));
        }
        // A frags: y[r,kstep] * x[r, l0+e]
        const float y0 = yr_[lr][kstep];
        const float y1 = yr_[16 + lr][kstep];
        bf16x8 af0, af1;
        #pragma unroll
        for (int e = 0; e < 8; ++e) {
            af0[e] = (short)__bfloat16_as_ushort(__float2bfloat16(y0 * xa0[e]));
            af1[e] = (short)__bfloat16_as_ushort(__float2bfloat16(y1 * xa1[e]));
        }
        acc0 = __builtin_amdgcn_mfma_f32_16x16x32_bf16(af0, bf, acc0, 0, 0, 0);
        acc1 = __builtin_amdgcn_mfma_f32_16x16x32_bf16(af1, bf, acc1, 0, 0, 0);
    }

    // ---- Epilogue: C row = lg*4+reg, col = lr; K-split reduce over 4 waves ----
    #pragma unroll
    for (int reg = 0; reg < 4; ++reg) {
        red2[wv][lg * 4 + reg][lr]      = acc0[reg];
        red2[wv][16 + lg * 4 + reg][lr] = acc1[reg];
    }
    __syncthreads();
    #pragma unroll
    for (int e = 0; e < 2; ++e) {                    // 512 outputs
        const int idx = e * THREADS + t;
        const int r = idx >> 4, o = idx & 15;
        const float v = red2[0][r][o] + red2[1][r][o] + red2[2][r][o] + red2[3][r][o];
        out[(b * N_ + i0 + r) * NORB_ + o0 + o] = v;
    }
}

extern "C" void kernel_launch(void* const* d_in, const int* in_sizes, int n_in,
                              void* d_out, int out_size, void* d_ws, size_t ws_size,
                              hipStream_t stream) {
    const float* chi = (const float*)d_in[0];
    const float* W   = (const float*)d_in[1];
    float* out = (float*)d_out;
    dim3 grid(B_ * (N_ / RPB) * (NORB_ / OPB));   // 8*4*8 = 256 blocks
    dim3 block(THREADS);
    hipLaunchKernelGGL(bobf_kernel, grid, block, 0, stream, chi, W, out);
}

// Round 15
// 9.673 us; speedup vs baseline: 1.6495x; 1.0188x over previous
//
#include <hip/hip_runtime.h>
#include <hip/hip_bf16.h>

#define B_    8
#define N_    128
#define NB_   32
#define NORB_ 128
#define RPB   32     // rows per block
#define OPB   16     // orbitals per block
#define THREADS 512

using bf16x8 = __attribute__((ext_vector_type(8))) short;
using f32x4  = __attribute__((ext_vector_type(4))) float;

__global__ __launch_bounds__(THREADS) void bobf_kernel(
    const float* __restrict__ chi,
    const float* __restrict__ W,
    float* __restrict__ out)
{
    __shared__ float Sp[16][NB_];                   // 2 KB
    __shared__ float S[NB_];
    __shared__ __align__(16) float xr_[RPB][36];    // x rows, 4.6 KB
    __shared__ float yr_[RPB][36];                  // y rows, 4.6 KB
    __shared__ float red2[8][RPB][20];              // 20.5 KB

    const int t   = threadIdx.x;
    const int blk = blockIdx.x;
    const int b    = blk >> 5;            // 0..7
    const int rowg = (blk >> 3) & 3;      // 0..3
    const int og   = blk & 7;             // 0..7
    const int i0   = rowg * RPB;
    const int o0   = og * OPB;

    const int wv   = t >> 6;              // 0..7 : wave owns ksteps wv*4..wv*4+3
    const int lane = t & 63;
    const int lr = lane & 15;             // A/C row-in-tile, B col
    const int lg = lane >> 4;             // k-group 0..3
    const int l0 = lg * 8;

    // ---- 1) B-fragment global loads, issued FIRST (32 dwords/lane) ----
    float wf[4][8];
    #pragma unroll
    for (int ks = 0; ks < 4; ++ks) {
        const int kstep = wv * 4 + ks;
        const float* wp = W + (kstep * 32 + l0) * NORB_ + o0 + lr;
        #pragma unroll
        for (int e = 0; e < 8; ++e)
            wf[ks][e] = wp[e * NORB_];
    }

    // ---- 2) S partials (coalesced) + x rows ----
    {
        const int k = t & 31;
        const int g = t >> 5;                        // 0..15, 8 rows each
        const float* base = chi + (b * N_) * NB_ + k;
        float s = 0.f;
        #pragma unroll
        for (int jj = 0; jj < 8; ++jj) s += base[(g * 8 + jj) * NB_];
        Sp[g][k] = s;
    }
    #pragma unroll
    for (int e = 0; e < 2; ++e) {                    // 1024 x-entries
        const int idx = e * THREADS + t;
        const int r = idx >> 5, l = idx & 31;
        xr_[r][l] = chi[(b * N_ + i0 + r) * NB_ + l];
    }
    __syncthreads();
    if (t < NB_) {
        float s = 0.f;
        #pragma unroll
        for (int g = 0; g < 16; ++g) s += Sp[g][t];
        S[t] = s;
    }
    __syncthreads();
    {
        const float inv = 1.0f / (float)(N_ - 1);
        #pragma unroll
        for (int e = 0; e < 2; ++e) {                // y[r][q] = (S[q]-x[r][q])/127
            const int idx = e * THREADS + t;
            const int r = idx >> 5, q = idx & 31;
            yr_[r][q] = (S[q] - xr_[r][q]) * inv;
        }
    }
    __syncthreads();

    // ---- 3) Convert B-frags; build A-frags for both M-tiles ----
    bf16x8 bfr[4];
    #pragma unroll
    for (int ks = 0; ks < 4; ++ks)
        #pragma unroll
        for (int e = 0; e < 8; ++e)
            bfr[ks][e] = (short)__bfloat16_as_ushort(__float2bfloat16(wf[ks][e]));

    float xa0[8], xa1[8];
    #pragma unroll
    for (int e = 0; e < 8; ++e) {
        xa0[e] = xr_[lr][l0 + e];
        xa1[e] = xr_[16 + lr][l0 + e];
    }

    bf16x8 af0[4], af1[4];
    #pragma unroll
    for (int ks = 0; ks < 4; ++ks) {
        const int kstep = wv * 4 + ks;
        const float y0 = yr_[lr][kstep];
        const float y1 = yr_[16 + lr][kstep];
        #pragma unroll
        for (int e = 0; e < 8; ++e) {
            af0[ks][e] = (short)__bfloat16_as_ushort(__float2bfloat16(y0 * xa0[e]));
            af1[ks][e] = (short)__bfloat16_as_ushort(__float2bfloat16(y1 * xa1[e]));
        }
    }

    // ---- 4) MFMA burst: 8 per wave ----
    f32x4 acc0 = {0.f, 0.f, 0.f, 0.f};
    f32x4 acc1 = {0.f, 0.f, 0.f, 0.f};
    #pragma unroll
    for (int ks = 0; ks < 4; ++ks) {
        acc0 = __builtin_amdgcn_mfma_f32_16x16x32_bf16(af0[ks], bfr[ks], acc0, 0, 0, 0);
        acc1 = __builtin_amdgcn_mfma_f32_16x16x32_bf16(af1[ks], bfr[ks], acc1, 0, 0, 0);
    }

    // ---- 5) Epilogue: C row = lg*4+reg, col = lr; reduce over 8 waves ----
    #pragma unroll
    for (int reg = 0; reg < 4; ++reg) {
        red2[wv][lg * 4 + reg][lr]      = acc0[reg];
        red2[wv][16 + lg * 4 + reg][lr] = acc1[reg];
    }
    __syncthreads();
    {
        const int r = t >> 4, o = t & 15;            // 512 outputs
        float v = 0.f;
        #pragma unroll
        for (int w8 = 0; w8 < 8; ++w8) v += red2[w8][r][o];
        out[(b * N_ + i0 + r) * NORB_ + o0 + o] = v;
    }
}

extern "C" void kernel_launch(void* const* d_in, const int* in_sizes, int n_in,
                              void* d_out, int out_size, void* d_ws, size_t ws_size,
                              hipStream_t stream) {
    const float* chi = (const float*)d_in[0];
    const float* W   = (const float*)d_in[1];
    float* out = (float*)d_out;
    dim3 grid(B_ * (N_ / RPB) * (NORB_ / OPB));   // 8*4*8 = 256 blocks
    dim3 block(THREADS);
    hipLaunchKernelGGL(bobf_kernel, grid, block, 0, stream, chi, W, out);
}